// Round 7
// baseline (237.744 us; speedup 1.0000x reference)
//
#include <hip/hip_runtime.h>
#include <hip/hip_bf16.h>

#define EDIM 256
#define NROWS 8192
#define NBT 64                          // 128-row blocks along each side
#define NBLOCKS (NBT * (NBT + 1) / 2)   // 2080 triangular block-tiles

typedef __attribute__((ext_vector_type(8))) short bf16x8;
typedef __attribute__((ext_vector_type(4))) float f32x4;

__device__ __forceinline__ unsigned short f2bf(float f) {
  unsigned int u = __float_as_uint(f);
  unsigned int r = (u + 0x7fffu + ((u >> 16) & 1u)) >> 16;  // RNE
  return (unsigned short)r;
}

__device__ __forceinline__ void gload_lds16(const void* g, void* l) {
  __builtin_amdgcn_global_load_lds(
      (const __attribute__((address_space(1))) unsigned int*)g,
      (__attribute__((address_space(3))) unsigned int*)l, 16, 0, 0);
}

// ---------------------------------------------------------------------------
// Kernel 1: normalize + transpose -> bf16 W[8192][256]; zero S and done.
// ---------------------------------------------------------------------------
__global__ __launch_bounds__(256) void detcon_normalize(
    const float* __restrict__ v0, const float* __restrict__ v1,
    __hip_bfloat16* __restrict__ Wb, float* __restrict__ S,
    unsigned int* __restrict__ done) {
  __shared__ float Xs[EDIM][32];
  __shared__ float part[4][32];
  __shared__ float scale_s[32];
  const int t = threadIdx.x;
  const int bid = blockIdx.x;              // 0..255
  if (t < 32) S[bid * 32 + t] = 0.0f;      // zero S (8192 = 256*32)
  if (bid == 0 && t == 0) *done = 0u;
  const int view = bid >> 7;
  const int b = (bid >> 1) & 63;
  const int nh = (bid & 1) * 32;
  const float* src = (view ? v1 : v0) + (size_t)b * (EDIM * 64);

  const int n4 = t & 7;
  const int eg = t >> 3;
  float4 ss = {0.f, 0.f, 0.f, 0.f};
#pragma unroll
  for (int i = 0; i < 8; ++i) {
    const int e = i * 32 + eg;
    float4 x = *(const float4*)(src + e * 64 + nh + n4 * 4);
    *(float4*)(&Xs[e][n4 * 4]) = x;
    ss.x += x.x * x.x; ss.y += x.y * x.y; ss.z += x.z * x.z; ss.w += x.w * x.w;
  }
#pragma unroll
  for (int m = 8; m <= 32; m <<= 1) {
    ss.x += __shfl_xor(ss.x, m, 64);
    ss.y += __shfl_xor(ss.y, m, 64);
    ss.z += __shfl_xor(ss.z, m, 64);
    ss.w += __shfl_xor(ss.w, m, 64);
  }
  if ((t & 63) < 8) *(float4*)(&part[t >> 6][(t & 7) * 4]) = ss;
  __syncthreads();
  if (t < 32) {
    const float total = part[0][t] + part[1][t] + part[2][t] + part[3][t];
    scale_s[t] = 3.16227766016838f / (sqrtf(total) + 1e-8f);
  }
  __syncthreads();

  const int nl = t >> 3;
  const int e0 = (t & 7) * 32;
  const float sc = scale_s[nl];
  const size_t r = (size_t)view * 4096 + (size_t)b * 64 + nh + nl;
  __hip_bfloat16* dst = Wb + r * EDIM;
#pragma unroll
  for (int j = 0; j < 4; ++j) {
    bf16x8 o;
#pragma unroll
    for (int u = 0; u < 8; ++u)
      o[u] = (short)f2bf(Xs[e0 + j * 8 + u][nl] * sc);
    *(bf16x8*)(dst + e0 + j * 8) = o;
  }
}

// ---------------------------------------------------------------------------
// Kernel 2: symmetric Gram + sum-of-exp. Only block-tiles (I,J) with J>=I.
// Block = 512 thr = 8 waves (2 wrow x 4 wcol) computing a 128x128 G tile in
// ONE K-shot (K=256 in a single 64KB LDS B-tile; A full-K in regs).
// Off-diag tiles contribute exp-sums to BOTH I-rows (row reduce) and J-rows
// (col reduce, via symmetry). Diag tiles: row sums only + sd capture;
// (I,I+32) tiles capture pd for both mirror rows. Last block finalizes.
// ---------------------------------------------------------------------------
__global__ __launch_bounds__(512, 2) void detcon_gram_sym(
    const __hip_bfloat16* __restrict__ Wbh, float* __restrict__ S,
    float* __restrict__ sd, float* __restrict__ pd,
    unsigned int* __restrict__ done, float* __restrict__ out) {
  __shared__ __align__(16) unsigned char b_lds[65536];
  __shared__ float red[8];
  __shared__ int lastFlag;
  const int tid = threadIdx.x;
  const int lane = tid & 63;
  const int wid = tid >> 6;                 // 0..7
  const int wr = wid >> 2;                  // 0..1
  const int wc = wid & 3;                   // 0..3

  // exact triangular decode: bid -> (I,J), 0 <= I <= J < 64; f(I)=I*(129-I)/2
  const int bid = blockIdx.x;
  int I = 0;
  {
    int lo = 0, hi = 63;
#pragma unroll
    for (int itr = 0; itr < 6; ++itr) {   // 6-step binary search, fixed count
      const int mid = (lo + hi + 1) >> 1;
      if (mid * (129 - mid) / 2 <= bid) lo = mid; else hi = mid - 1;
    }
    I = lo;
  }
  const int J = I + (bid - I * (129 - I) / 2);

  const int rowbase = I * 128 + wr * 64;
  const int colbase = J * 128;
  const unsigned short* W = (const unsigned short*)Wbh;
  const char* Wbytes = (const char*)Wbh;

  // ---- stage B tile: 128 cols x 512B, source-side XOR swizzle ----
#pragma unroll
  for (int i = 0; i < 8; ++i) {
    const int cl = wid * 16 + i * 2 + (lane >> 5);
    const char* g = Wbytes + ((size_t)(colbase + cl) << 9) +
                    (((lane & 31) * 16) ^ ((cl & 7) << 4));
    gload_lds16(g, &b_lds[wid * 8192 + i * 1024]);
  }

  // ---- A fragments, full K (overlaps with staging loads) ----
  bf16x8 a[4][8];
#pragma unroll
  for (int m = 0; m < 4; ++m) {
    const unsigned row = rowbase + m * 16 + (lane & 15);
#pragma unroll
    for (int kb = 0; kb < 8; ++kb)
      a[m][kb] = *(const bf16x8*)(W + (row << 8) + kb * 32 + (lane >> 4) * 8);
  }

  f32x4 acc[4][2];
#pragma unroll
  for (int m = 0; m < 4; ++m)
#pragma unroll
    for (int n = 0; n < 2; ++n) acc[m][n] = (f32x4){0.f, 0.f, 0.f, 0.f};

  __syncthreads();  // B tile ready

  // ---- compute: wave = 64 rows x 32 cols, 64 MFMA ----
#pragma unroll
  for (int kb = 0; kb < 8; ++kb) {
    bf16x8 bfrag[2];
#pragma unroll
    for (int n = 0; n < 2; ++n) {
      const int cl = wc * 32 + n * 16 + (lane & 15);
      const int addr = (cl << 9) + ((kb * 64 + (lane >> 4) * 16) ^ ((cl & 7) << 4));
      bfrag[n] = *(const bf16x8*)(b_lds + addr);
    }
#pragma unroll
    for (int m = 0; m < 4; ++m)
#pragma unroll
      for (int n = 0; n < 2; ++n)
        acc[m][n] = __builtin_amdgcn_mfma_f32_16x16x32_bf16(a[m][kb], bfrag[n],
                                                            acc[m][n], 0, 0, 0);
  }

  // ---- epilogue: exp, row sums, symmetric col sums, sd/pd capture ----
  const bool diagB = (J == I);
  const bool posB = (J == I + 32);
  float srow[4][4];
  float scol[2] = {0.f, 0.f};
#pragma unroll
  for (int m = 0; m < 4; ++m)
#pragma unroll
    for (int j = 0; j < 4; ++j) srow[m][j] = 0.f;

#pragma unroll
  for (int m = 0; m < 4; ++m) {
#pragma unroll
    for (int n = 0; n < 2; ++n) {
#pragma unroll
      for (int j = 0; j < 4; ++j) {
        const float g = acc[m][n][j];
        const float e = __expf(g);
        srow[m][j] += e;
        scol[n] += e;
        if (diagB || posB) {
          const int grl = wr * 64 + m * 16 + (lane >> 4) * 4 + j;  // 0..127
          const int gcl = wc * 32 + n * 16 + (lane & 15);          // 0..127
          if (gcl == grl) {
            if (diagB) sd[I * 128 + grl] = g;
            else { pd[I * 128 + grl] = g; pd[J * 128 + gcl] = g; }
          }
        }
      }
    }
  }

  // row sums -> S[I-rows]
#pragma unroll
  for (int m = 0; m < 4; ++m) {
#pragma unroll
    for (int j = 0; j < 4; ++j) {
      float v = srow[m][j];
      v += __shfl_xor(v, 1, 64);
      v += __shfl_xor(v, 2, 64);
      v += __shfl_xor(v, 4, 64);
      v += __shfl_xor(v, 8, 64);
      if ((lane & 15) == 0)
        atomicAdd(&S[rowbase + m * 16 + (lane >> 4) * 4 + j], v);
    }
  }
  // col sums -> S[J-rows] via symmetry (off-diag only)
  if (J > I) {
#pragma unroll
    for (int n = 0; n < 2; ++n) {
      float v = scol[n];
      v += __shfl_xor(v, 16, 64);
      v += __shfl_xor(v, 32, 64);
      if (lane < 16)
        atomicAdd(&S[colbase + wc * 32 + n * 16 + lane], v);
    }
  }

  // ---- grid completion: last block finalizes ----
  __syncthreads();
  if (tid == 0) {
    __threadfence();
    lastFlag = (atomicAdd(done, 1u) == (unsigned)(NBLOCKS - 1));
  }
  __syncthreads();
  if (lastFlag) {
    __threadfence();
    float local = 0.f;
    for (int r = tid; r < NROWS; r += 512)
      local += logf(S[r] - __expf(sd[r])) - pd[r];
#pragma unroll
    for (int m = 32; m >= 1; m >>= 1) local += __shfl_xor(local, m, 64);
    if ((tid & 63) == 0) red[tid >> 6] = local;
    __syncthreads();
    if (tid == 0) {
      float t = 0.f;
#pragma unroll
      for (int w = 0; w < 8; ++w) t += red[w];
      out[0] = t * (1.0f / (float)NROWS);
    }
  }
}

extern "C" void kernel_launch(void* const* d_in, const int* in_sizes, int n_in,
                              void* d_out, int out_size, void* d_ws, size_t ws_size,
                              hipStream_t stream) {
  const float* v0 = (const float*)d_in[0];
  const float* v1 = (const float*)d_in[1];
  float* out = (float*)d_out;

  // ws: Wb bf16[8192][256] | S f32[8192] | sd f32[8192] | pd f32[8192] | done u32
  __hip_bfloat16* Wb = (__hip_bfloat16*)d_ws;
  char* base = (char*)d_ws + (size_t)NROWS * EDIM * 2;
  float* S = (float*)base;
  float* sd = S + NROWS;
  float* pd = sd + NROWS;
  unsigned int* done = (unsigned int*)(pd + NROWS);

  detcon_normalize<<<256, 256, 0, stream>>>(v0, v1, Wb, S, done);
  detcon_gram_sym<<<NBLOCKS, 512, 0, stream>>>(Wb, S, sd, pd, done, out);
}

// Round 9
// 122.640 us; speedup vs baseline: 1.9386x; 1.9386x over previous
//
#include <hip/hip_runtime.h>
#include <hip/hip_bf16.h>

#define EDIM 256
#define NROWS 8192
#define GRIDX 8
#define GRIDY 64
#define NBLOCKS (GRIDX * GRIDY)   // 512

typedef __attribute__((ext_vector_type(8))) short bf16x8;
typedef __attribute__((ext_vector_type(4))) float f32x4;

__device__ __forceinline__ unsigned short f2bf(float f) {
  unsigned int u = __float_as_uint(f);
  unsigned int r = (u + 0x7fffu + ((u >> 16) & 1u)) >> 16;  // RNE
  return (unsigned short)r;
}

__device__ __forceinline__ void gload_lds16(const void* g, void* l) {
  __builtin_amdgcn_global_load_lds(
      (const __attribute__((address_space(1))) unsigned int*)g,
      (__attribute__((address_space(3))) unsigned int*)l, 16, 0, 0);
}

// ---------------------------------------------------------------------------
// Kernel 1: normalize + transpose -> bf16 W[8192][256]; zero S and done.
// ---------------------------------------------------------------------------
__global__ __launch_bounds__(256) void detcon_normalize(
    const float* __restrict__ v0, const float* __restrict__ v1,
    __hip_bfloat16* __restrict__ Wb, float* __restrict__ S,
    unsigned int* __restrict__ done) {
  __shared__ float Xs[EDIM][32];
  __shared__ float part[4][32];
  __shared__ float scale_s[32];
  const int t = threadIdx.x;
  const int bid = blockIdx.x;              // 0..255
  if (t < 32) S[bid * 32 + t] = 0.0f;      // zero S (8192 = 256*32)
  if (bid == 0 && t == 0) *done = 0u;
  const int view = bid >> 7;
  const int b = (bid >> 1) & 63;
  const int nh = (bid & 1) * 32;
  const float* src = (view ? v1 : v0) + (size_t)b * (EDIM * 64);

  const int n4 = t & 7;
  const int eg = t >> 3;
  float4 ss = {0.f, 0.f, 0.f, 0.f};
#pragma unroll
  for (int i = 0; i < 8; ++i) {
    const int e = i * 32 + eg;
    float4 x = *(const float4*)(src + e * 64 + nh + n4 * 4);
    *(float4*)(&Xs[e][n4 * 4]) = x;
    ss.x += x.x * x.x; ss.y += x.y * x.y; ss.z += x.z * x.z; ss.w += x.w * x.w;
  }
#pragma unroll
  for (int m = 8; m <= 32; m <<= 1) {
    ss.x += __shfl_xor(ss.x, m, 64);
    ss.y += __shfl_xor(ss.y, m, 64);
    ss.z += __shfl_xor(ss.z, m, 64);
    ss.w += __shfl_xor(ss.w, m, 64);
  }
  if ((t & 63) < 8) *(float4*)(&part[t >> 6][(t & 7) * 4]) = ss;
  __syncthreads();
  if (t < 32) {
    const float total = part[0][t] + part[1][t] + part[2][t] + part[3][t];
    scale_s[t] = 3.16227766016838f / (sqrtf(total) + 1e-8f);
  }
  __syncthreads();

  const int nl = t >> 3;
  const int e0 = (t & 7) * 32;
  const float sc = scale_s[nl];
  const size_t r = (size_t)view * 4096 + (size_t)b * 64 + nh + nl;
  __hip_bfloat16* dst = Wb + r * EDIM;
#pragma unroll
  for (int j = 0; j < 4; ++j) {
    bf16x8 o;
#pragma unroll
    for (int u = 0; u < 8; ++u)
      o[u] = (short)f2bf(Xs[e0 + j * 8 + u][nl] * sc);
    *(bf16x8*)(dst + e0 + j * 8) = o;
  }
}

// ---------------------------------------------------------------------------
// Kernel 2: fused Gram + sum-of-exp. Grid (8,64)=512 blocks, 2 blocks/CU.
// Block = 128 rows x 1024 cols, 512 thr = 8 waves as 4 wrow x 2 wcol:
// per-wave A = 32 rows full-K in regs (64 VGPR) -> ~120 regs/wave ->
// 4 waves/SIMD from TWO independent blocks (TLP hides barrier/stage drain).
// 64-col double-buffered LDS tiles, source-side XOR swizzle, one barrier/iter.
// In-loop sd/pd extraction; done-counter finalize in the last block.
// ---------------------------------------------------------------------------
__global__ __launch_bounds__(512, 4) void detcon_gram(
    const __hip_bfloat16* __restrict__ Wbh, float* __restrict__ S,
    float* __restrict__ sd, float* __restrict__ pd,
    unsigned int* __restrict__ done, float* __restrict__ out) {
  __shared__ __align__(16) unsigned char b_lds[2][32768];
  __shared__ float red[8];
  __shared__ int lastFlag;
  const int tid = threadIdx.x;
  const int lane = tid & 63;
  const int wid = tid >> 6;        // 0..7
  const int wr = wid >> 1;         // 0..3
  const int wc = wid & 1;          // 0..1
  const int rowbase = blockIdx.y * 128;
  const int wrowbase = rowbase + wr * 32;   // wave's 32-row strip
  const int colblock = blockIdx.x * 1024;
  const unsigned short* W = (const unsigned short*)Wbh;
  const char* Wbytes = (const char*)Wbh;

  // A fragments, full K: lane holds A[wrowbase+m*16+(lane&15)][kb*32+(lane>>4)*8 ..+8]
  bf16x8 a[2][8];
#pragma unroll
  for (int m = 0; m < 2; ++m) {
    const unsigned row = wrowbase + m * 16 + (lane & 15);
#pragma unroll
    for (int kb = 0; kb < 8; ++kb)
      a[m][kb] = *(const bf16x8*)(W + (row << 8) + kb * 32 + (lane >> 4) * 8);
  }

  f32x4 acc[2][2];
  float s[2][4];
#pragma unroll
  for (int m = 0; m < 2; ++m) {
#pragma unroll
    for (int n = 0; n < 2; ++n) acc[m][n] = (f32x4){0.f, 0.f, 0.f, 0.f};
#pragma unroll
    for (int j = 0; j < 4; ++j) s[m][j] = 0.f;
  }

  // Stage 64 cols x 512 B (32 KB) with all 512 threads, source-side swizzle.
  const int stage_cl = wid * 8 + (lane >> 5);   // + i*2
  const int stage_inner = (lane & 31) * 16;

#define STAGE(BUF, CB)                                                         \
  {                                                                            \
    _Pragma("unroll")                                                          \
    for (int i = 0; i < 4; ++i) {                                              \
      const int cl = stage_cl + i * 2;                                         \
      const char* g = Wbytes + ((size_t)((CB) + cl) << 9) +                    \
                      (stage_inner ^ ((cl & 7) << 4));                         \
      gload_lds16(g, &b_lds[BUF][wid * 4096 + i * 1024]);                      \
    }                                                                          \
  }

  STAGE(0, colblock);
  __syncthreads();

  const int jl = (lane & 15) - ((lane >> 4) << 2);
  int cur = 0;
  for (int it = 0; it < 16; ++it) {
    if (it < 15) STAGE(cur ^ 1, colblock + (it + 1) * 64);

    // ---- compute: wave = 32 rows x 64 cols (2 n-strips of 16) ----
#pragma unroll
    for (int kb = 0; kb < 8; ++kb) {
      bf16x8 bfrag[2];
#pragma unroll
      for (int n = 0; n < 2; ++n) {
        const int cl = wc * 32 + n * 16 + (lane & 15);
        const int addr =
            (cl << 9) + ((kb * 64 + (lane >> 4) * 16) ^ ((cl & 7) << 4));
        bfrag[n] = *(const bf16x8*)(&b_lds[cur][0] + addr);
      }
#pragma unroll
      for (int m = 0; m < 2; ++m)
#pragma unroll
        for (int n = 0; n < 2; ++n)
          acc[m][n] = __builtin_amdgcn_mfma_f32_16x16x32_bf16(
              a[m][kb], bfrag[n], acc[m][n], 0, 0, 0);
    }

    // ---- epilogue per n-strip: sd/pd extraction + exp-accumulate ----
#pragma unroll
    for (int n = 0; n < 2; ++n) {
      const int strip0 = colblock + it * 64 + wc * 32 + n * 16;
      const unsigned d0 = (unsigned)(strip0 - wrowbase);
      if (d0 < 32u) {   // diagonal crosses this strip (wave-uniform, rare)
        const int dm = (int)(d0 >> 4);
#pragma unroll
        for (int m = 0; m < 2; ++m)
          if (m == dm) {
#pragma unroll
            for (int j = 0; j < 4; ++j)
              if (j == jl) sd[strip0 + (lane & 15)] = acc[m][n][j];
          }
      }
      const unsigned p0 = (unsigned)(((strip0 + 4096) & 8191) - wrowbase);
      if (p0 < 32u) {   // positive-pair band crosses this strip
        const int pm = (int)(p0 >> 4);
#pragma unroll
        for (int m = 0; m < 2; ++m)
          if (m == pm) {
#pragma unroll
            for (int j = 0; j < 4; ++j)
              if (j == jl)
                pd[(strip0 + (lane & 15) + 4096) & 8191] = acc[m][n][j];
          }
      }
#pragma unroll
      for (int m = 0; m < 2; ++m) {
#pragma unroll
        for (int j = 0; j < 4; ++j) s[m][j] += __expf(acc[m][n][j]);
        acc[m][n] = (f32x4){0.f, 0.f, 0.f, 0.f};
      }
    }
    __syncthreads();   // drains next-tile stage (issued a full phase ago)
    cur ^= 1;
  }

  // ---- per-row sums: 16-lane shuffle reduce, one atomic per row ----
#pragma unroll
  for (int m = 0; m < 2; ++m) {
#pragma unroll
    for (int j = 0; j < 4; ++j) {
      float v = s[m][j];
      v += __shfl_xor(v, 1, 64);
      v += __shfl_xor(v, 2, 64);
      v += __shfl_xor(v, 4, 64);
      v += __shfl_xor(v, 8, 64);
      if ((lane & 15) == 0)
        atomicAdd(&S[wrowbase + m * 16 + (lane >> 4) * 4 + j], v);
    }
  }

  // ---- grid completion: last block finalizes ----
  __syncthreads();
  if (tid == 0) {
    __threadfence();
    lastFlag = (atomicAdd(done, 1u) == (unsigned)(NBLOCKS - 1));
  }
  __syncthreads();
  if (lastFlag) {
    __threadfence();
    float local = 0.f;
    for (int r = tid; r < NROWS; r += 512)
      local += logf(S[r] - __expf(sd[r])) - pd[r];
#pragma unroll
    for (int m = 32; m >= 1; m >>= 1) local += __shfl_xor(local, m, 64);
    if ((tid & 63) == 0) red[tid >> 6] = local;
    __syncthreads();
    if (tid == 0) {
      float t = 0.f;
#pragma unroll
      for (int w = 0; w < 8; ++w) t += red[w];
      out[0] = t * (1.0f / (float)NROWS);
    }
  }
#undef STAGE
}

extern "C" void kernel_launch(void* const* d_in, const int* in_sizes, int n_in,
                              void* d_out, int out_size, void* d_ws, size_t ws_size,
                              hipStream_t stream) {
  const float* v0 = (const float*)d_in[0];
  const float* v1 = (const float*)d_in[1];
  float* out = (float*)d_out;

  // ws: Wb bf16[8192][256] | S f32[8192] | sd f32[8192] | pd f32[8192] | done u32
  __hip_bfloat16* Wb = (__hip_bfloat16*)d_ws;
  char* base = (char*)d_ws + (size_t)NROWS * EDIM * 2;
  float* S = (float*)base;
  float* sd = S + NROWS;
  float* pd = sd + NROWS;
  unsigned int* done = (unsigned int*)(pd + NROWS);

  detcon_normalize<<<256, 256, 0, stream>>>(v0, v1, Wb, S, done);
  detcon_gram<<<dim3(GRIDX, GRIDY), 512, 0, stream>>>(Wb, S, sd, pd, done, out);
}